// Round 1
// 765.833 us; speedup vs baseline: 1.1930x; 1.1930x over previous
//
#include <hip/hip_runtime.h>
#include <hip/hip_bf16.h>

// DGWA fused, MFMA version, 2-blocks/CU edition.
// One block per window (8192 blocks x 512 threads). LDS cut 148KB -> 75.3KB by
// reading weight B-fragments directly from global (L2-resident, shared by all
// blocks) instead of staging into LDS, plus tighter phase-aliasing. This lifts
// occupancy from 1 block/CU (8 waves) to 2 blocks/CU (16 waves) so the barrier
// chain of one block overlaps the compute of the other.
// All matmuls on v_mfma_f32_16x16x32_bf16 with K-contiguous LDS layouts:
//   A-frag: A[m=lane&15][k=quad*8+j]   (row-major [M][K])
//   B-frag: B[k=quad*8+j][n=lane&15]   (store B^T row-major [N][K])
//   C/D:    row=quad*4+reg, col=lane&15
// Chain trick: sim^T = K·Q^T, out^T = V^T·P, final^T = o_w^T·attn -> every
// operand reads natural K-contiguous rows (ds_read_b128), every transpose is
// a 2-way-conflict bf16 scatter from C-frags.
// Prep kernel packs transposed bf16 weights into d_ws once per call.

#define WS_    8
#define SHIFT_ 4
#define C_     128
#define IMG_   256

typedef __attribute__((ext_vector_type(8))) short short8;
typedef __attribute__((ext_vector_type(4))) short short4v;
typedef __attribute__((ext_vector_type(4))) float f32x4;

#define MFMA(a,b,c) __builtin_amdgcn_mfma_f32_16x16x32_bf16((a),(b),(c),0,0,0)

__device__ __forceinline__ short f2bf(float f){
    unsigned u = __float_as_uint(f);
    u = u + 0x7fffu + ((u >> 16) & 1u);   // round-to-nearest-even
    return (short)(u >> 16);
}
__device__ __forceinline__ float bf2f(short s){
    return __uint_as_float(((unsigned)(unsigned short)s) << 16);
}

// ws (bf16): [0,16384) q_wT[cout][cin]; [16384,49152) kv_wT[cout][cin]; [49152,65536) o_wT[cout][cin]
__global__ void dgwa_prep(const float* __restrict__ q_w, const float* __restrict__ kv_w,
                          const float* __restrict__ o_w, short* __restrict__ ws){
    int idx = blockIdx.x*256 + threadIdx.x;
    if (idx < 16384){ int co = idx>>7, ci = idx&127; ws[idx] = f2bf(q_w[ci*128 + co]); }
    else if (idx < 49152){ int i = idx-16384; int co = i>>7, ci = i&127; ws[idx] = f2bf(kv_w[ci*256 + co]); }
    else { int i = idx-49152; int co = i>>7, ci = i&127; ws[idx] = f2bf(o_w[ci*128 + co]); }
}

__global__ __launch_bounds__(512, 4)
void dgwa_fused(const float* __restrict__ x, const float* __restrict__ rpp,
                const float* __restrict__ wi_w, const float* __restrict__ wi_b,
                const float* __restrict__ w1_w, const float* __restrict__ w1_b,
                const float* __restrict__ w2_w, const float* __restrict__ w2_b,
                const float* __restrict__ q_b,  const float* __restrict__ kv_b,
                const float* __restrict__ o_b,
                const short* __restrict__ wsw,
                float* __restrict__ out)
{
    // Region map (byte offsets), phase-aliased. Total 75,296 B -> 2 blocks/CU.
    //   [0)      s_xw  [64][136] bf16: xw (P0->P4) -> q (P4->P5) -> attn (P6->P7)
    //   [17408)  s_xd2 [64][136] (P2->P3)
    //            s_p   [4][64][68] bf16 alias over s_xd2+s_k (P5mid->P6)
    //            s_outT[128][66] f32 alias over same region (P7->P8)
    //   [34816)  s_k   [64][136] (P3->P5a); s_xd [64][136] alias (P1->P2)
    //   [52224)  s_vT  [128][72] (P3->P6)
    //   [70656)  s_rpp[900] f32; [74256) s_off[128]; [74768) s_red[128]; [75280) s_oi[2]
    __shared__ __align__(16) char smem[75296];
    short* s_xw   = (short*)(smem);
    short* s_xd2  = (short*)(smem + 17408);
    short* s_p    = (short*)(smem + 17408);
    float* s_outT = (float*)(smem + 17408);
    short* s_k    = (short*)(smem + 34816);
    short* s_xd   = (short*)(smem + 34816);
    short* s_vT   = (short*)(smem + 52224);
    float* s_rpp  = (float*)(smem + 70656);
    float* s_off  = (float*)(smem + 74256);
    float* s_red  = (float*)(smem + 74768);
    float* s_oi   = (float*)(smem + 75280);

    const int t   = threadIdx.x;
    const int wv  = t >> 6, l = t & 63, l15 = l & 15, quad = l >> 4;
    const int win = blockIdx.x;
    const int bb  = win >> 10, wy = (win >> 5) & 31, wx = win & 31;
    const f32x4 zf = {0.f, 0.f, 0.f, 0.f};

    const short* qw  = wsw;           // q_wT  [128][128]
    const short* kvw = wsw + 16384;   // kv_wT [256][128]
    const short* ow  = wsw + 49152;   // o_wT  [128][128]

    // ---------------- P0: offset projections + stage xw (bf16) ----------------------
    {
        const int tok = t >> 3, part = t & 7;          // 16 chans per thread
        const int i = tok >> 3, j = tok & 7;
        const int grow = (wy*8 + i + SHIFT_) & 255;
        const int gcol = (wx*8 + j + SHIFT_) & 255;
        const float* xr = x + (((size_t)bb*IMG_ + grow)*IMG_ + gcol)*C_ + part*16;
        float di0=0.f, di1=0.f, d10=0.f, d11=0.f;
        #pragma unroll
        for (int c4 = 0; c4 < 4; ++c4){
            const float4 a4 = *(const float4*)(xr + c4*4);
            const int ch = part*16 + c4*4;
            di0 += a4.x*wi_w[ch*2+0]+a4.y*wi_w[ch*2+2]+a4.z*wi_w[ch*2+4]+a4.w*wi_w[ch*2+6];
            di1 += a4.x*wi_w[ch*2+1]+a4.y*wi_w[ch*2+3]+a4.z*wi_w[ch*2+5]+a4.w*wi_w[ch*2+7];
            d10 += a4.x*w1_w[ch*2+0]+a4.y*w1_w[ch*2+2]+a4.z*w1_w[ch*2+4]+a4.w*w1_w[ch*2+6];
            d11 += a4.x*w1_w[ch*2+1]+a4.y*w1_w[ch*2+3]+a4.z*w1_w[ch*2+5]+a4.w*w1_w[ch*2+7];
            short4v sv = { f2bf(a4.x), f2bf(a4.y), f2bf(a4.z), f2bf(a4.w) };
            *(short4v*)&s_xw[tok*136 + part*16 + c4*4] = sv;
        }
        di0 += __shfl_xor(di0,1); di0 += __shfl_xor(di0,2); di0 += __shfl_xor(di0,4);
        di1 += __shfl_xor(di1,1); di1 += __shfl_xor(di1,2); di1 += __shfl_xor(di1,4);
        d10 += __shfl_xor(d10,1); d10 += __shfl_xor(d10,2); d10 += __shfl_xor(d10,4);
        d11 += __shfl_xor(d11,1); d11 += __shfl_xor(d11,2); d11 += __shfl_xor(d11,4);
        if (part == 0){
            s_off[tok*2+0] = di0 + wi_b[0];
            s_off[tok*2+1] = di1 + wi_b[1];
            s_red[tok*2+0] = d10 + w1_b[0];
            s_red[tok*2+1] = d11 + w1_b[1];
        }
    }
    for (int idx = t; idx < 900; idx += 512) s_rpp[idx] = rpp[idx];
    __syncthreads();
    if (t < 64){
        const float a0 = s_red[t*2+0], a1 = s_red[t*2+1];
        float p0 = a0*w2_w[(t*2+0)*2+0] + a1*w2_w[(t*2+1)*2+0];
        float p1 = a0*w2_w[(t*2+0)*2+1] + a1*w2_w[(t*2+1)*2+1];
        #pragma unroll
        for (int m = 1; m < 64; m <<= 1){ p0 += __shfl_xor(p0,m); p1 += __shfl_xor(p1,m); }
        if (t == 0){ s_oi[0] = p0 + w2_b[0]; s_oi[1] = p1 + w2_b[1]; }
    }
    __syncthreads();

    // ---------------- P1: inter-window bilinear sample -> s_xd (bf16) ---------------
    {
        const int tok = t >> 3, part = t & 7;
        const int i = tok >> 3, j = tok & 7;
        const float gx = (float)wx + s_oi[0];
        const float gy = (float)wy + s_oi[1];
        const float fx0 = floorf(gx), fy0 = floorf(gy);
        const int ix0 = (int)fx0, iy0 = (int)fy0;
        const float fx = gx - fx0, fy = gy - fy0;
        const float cw[4] = {(1.f-fx)*(1.f-fy), fx*(1.f-fy), (1.f-fx)*fy, fx*fy};
        float4 acc4[4];
        #pragma unroll
        for (int c4 = 0; c4 < 4; ++c4) acc4[c4] = make_float4(0.f,0.f,0.f,0.f);
        #pragma unroll
        for (int cc = 0; cc < 4; ++cc){
            const int cx = ix0 + (cc & 1), cy = iy0 + (cc >> 1);
            if (cx >= 0 && cx < 32 && cy >= 0 && cy < 32){    // wave-uniform
                const int rr = (cy*8 + i + SHIFT_) & 255;
                const int cl = (cx*8 + j + SHIFT_) & 255;
                const float* p = x + (((size_t)bb*IMG_ + rr)*IMG_ + cl)*C_ + part*16;
                const float w = cw[cc];
                #pragma unroll
                for (int c4 = 0; c4 < 4; ++c4){
                    const float4 v = *(const float4*)(p + c4*4);
                    acc4[c4].x += w*v.x; acc4[c4].y += w*v.y;
                    acc4[c4].z += w*v.z; acc4[c4].w += w*v.w;
                }
            }
        }
        #pragma unroll
        for (int c4 = 0; c4 < 4; ++c4){
            short4v sv = { f2bf(acc4[c4].x), f2bf(acc4[c4].y), f2bf(acc4[c4].z), f2bf(acc4[c4].w) };
            *(short4v*)&s_xd[tok*136 + part*16 + c4*4] = sv;
        }
    }
    __syncthreads();

    // ---------------- P2: intra-window bilinear sample -> s_xd2 (bf16) --------------
    {
        const int tok = t >> 3, part = t & 7;
        const int i = tok >> 3, j = tok & 7;
        const float sx = (float)j + s_off[tok*2+0];
        const float sy = (float)i + s_off[tok*2+1];
        const float fx0 = floorf(sx), fy0 = floorf(sy);
        const int jx0 = (int)fx0, jy0 = (int)fy0;
        const float fx = sx - fx0, fy = sy - fy0;
        float4 acc4[4];
        #pragma unroll
        for (int c4 = 0; c4 < 4; ++c4) acc4[c4] = make_float4(0.f,0.f,0.f,0.f);
        #pragma unroll
        for (int cc = 0; cc < 4; ++cc){
            const int cx = jx0 + (cc & 1), cy = jy0 + (cc >> 1);
            const float w = ((cc & 1) ? fx : 1.f-fx) * ((cc >> 1) ? fy : 1.f-fy);
            if (cx >= 0 && cx < 8 && cy >= 0 && cy < 8){
                const short* p = &s_xd[(cy*8 + cx)*136 + part*16];
                #pragma unroll
                for (int c4 = 0; c4 < 4; ++c4){
                    const short4v sv = *(const short4v*)(p + c4*4);
                    acc4[c4].x += w*bf2f(sv.x); acc4[c4].y += w*bf2f(sv.y);
                    acc4[c4].z += w*bf2f(sv.z); acc4[c4].w += w*bf2f(sv.w);
                }
            }
        }
        #pragma unroll
        for (int c4 = 0; c4 < 4; ++c4){
            short4v sv = { f2bf(acc4[c4].x), f2bf(acc4[c4].y), f2bf(acc4[c4].z), f2bf(acc4[c4].w) };
            *(short4v*)&s_xd2[tok*136 + part*16 + c4*4] = sv;
        }
    }
    __syncthreads();

    // ---------------- P3: kv = xd2 @ kv_w (weights from global/L2) ------------------
    //                  k -> s_k, v -> s_vT
    {
        f32x4 acc[2][4];
        #pragma unroll
        for (int nn = 0; nn < 2; ++nn)
            #pragma unroll
            for (int mt = 0; mt < 4; ++mt) acc[nn][mt] = zf;
        #pragma unroll
        for (int ks = 0; ks < 4; ++ks){
            const int co = ks*32 + quad*8;
            const short8 b0 = *(const short8*)&kvw[(32*wv +      l15)*128 + co];
            const short8 b1 = *(const short8*)&kvw[(32*wv + 16 + l15)*128 + co];
            #pragma unroll
            for (int mt = 0; mt < 4; ++mt){
                const short8 a = *(const short8*)&s_xd2[(16*mt + l15)*136 + co];
                acc[0][mt] = MFMA(a, b0, acc[0][mt]);
                acc[1][mt] = MFMA(a, b1, acc[1][mt]);
            }
        }
        #pragma unroll
        for (int nn = 0; nn < 2; ++nn){
            const int col = 32*wv + 16*nn + l15;
            const float bias = kv_b[col];
            if (col < 128){                                  // waves 0..3 -> K
                #pragma unroll
                for (int mt = 0; mt < 4; ++mt)
                    #pragma unroll
                    for (int r = 0; r < 4; ++r){
                        const int tokr = 16*mt + 4*quad + r;
                        s_k[tokr*136 + col] = f2bf(acc[nn][mt][r] + bias);
                    }
            } else {                                         // waves 4..7 -> V^T (packed dword)
                const int vr = col - 128;
                #pragma unroll
                for (int mt = 0; mt < 4; ++mt)
                    #pragma unroll
                    for (int rp = 0; rp < 2; ++rp){
                        const int tokr = 16*mt + 4*quad + 2*rp;
                        const unsigned lo = (unsigned short)f2bf(acc[nn][mt][2*rp]   + bias);
                        const unsigned hi = (unsigned short)f2bf(acc[nn][mt][2*rp+1] + bias);
                        *(unsigned*)&s_vT[vr*72 + tokr] = lo | (hi << 16);
                    }
            }
        }
    }
    __syncthreads();

    // ---------------- P4: q = xw @ q_w (weights from global/L2) -> s_xw -------------
    {
        f32x4 qacc[4];
        #pragma unroll
        for (int mt = 0; mt < 4; ++mt) qacc[mt] = zf;
        #pragma unroll
        for (int ks = 0; ks < 4; ++ks){
            const int co = ks*32 + quad*8;
            const short8 b = *(const short8*)&qw[(16*wv + l15)*128 + co];
            #pragma unroll
            for (int mt = 0; mt < 4; ++mt){
                const short8 a = *(const short8*)&s_xw[(16*mt + l15)*136 + co];
                qacc[mt] = MFMA(a, b, qacc[mt]);
            }
        }
        __syncthreads();     // all s_xw reads complete before q overwrites it
        const int col = 16*wv + l15;
        const float bias = q_b[col];
        #pragma unroll
        for (int mt = 0; mt < 4; ++mt)
            #pragma unroll
            for (int r = 0; r < 4; ++r)
                s_xw[(16*mt + 4*quad + r)*136 + col] = f2bf(qacc[mt][r] + bias);
    }
    __syncthreads();

    // ---------------- P5: waves 0-3: sim^T = K·Q^T, softmax, P -> s_p ---------------
    // s_p aliases s_xd2+s_k, so K/Q fragments go to registers BEFORE the mid barrier.
    short8 ka[4], bq[4];
    if (wv < 4){
        const int h = wv;
        #pragma unroll
        for (int mt = 0; mt < 4; ++mt)
            ka[mt] = *(const short8*)&s_k [(16*mt + l15)*136 + 32*h + quad*8];
        #pragma unroll
        for (int nt = 0; nt < 4; ++nt)
            bq[nt] = *(const short8*)&s_xw[(16*nt + l15)*136 + 32*h + quad*8];  // q
    }
    __syncthreads();         // s_k dead; s_p may now overwrite it
    if (wv < 4){
        const int h = wv;
        const bool mrow = (wy == 31), mcol = (wx == 31);
        #pragma unroll
        for (int nt = 0; nt < 4; ++nt){
            f32x4 sc[4];
            #pragma unroll
            for (int mt = 0; mt < 4; ++mt)
                sc[mt] = MFMA(ka[mt], bq[nt], zf);
            const int qtok = 16*nt + l15;
            const int iq = qtok >> 3, jq = qtok & 7;
            float ssum = 0.f;
            #pragma unroll
            for (int mt = 0; mt < 4; ++mt){
                #pragma unroll
                for (int r = 0; r < 4; ++r){
                    const int ktok = 16*mt + 4*quad + r;
                    const int ik = ktok >> 3, jk = ktok & 7;
                    const float sv = sc[mt][r]*0.1767766952966369f
                                   + s_rpp[h*225 + (iq-ik+7)*15 + (jq-jk+7)];
                    const bool masked = (mrow && ((iq<4)!=(ik<4))) || (mcol && ((jq<4)!=(jk<4)));
                    const float e = masked ? 0.f : __expf(sv);   // |logit| small: no max-sub needed
                    sc[mt][r] = e;
                    ssum += e;
                }
            }
            ssum += __shfl_xor(ssum, 16);
            ssum += __shfl_xor(ssum, 32);
            const float rs = 1.f / ssum;
            #pragma unroll
            for (int mt = 0; mt < 4; ++mt)
                #pragma unroll
                for (int rp = 0; rp < 2; ++rp){
                    const int ktok = 16*mt + 4*quad + 2*rp;
                    const unsigned lo = (unsigned short)f2bf(sc[mt][2*rp]   * rs);
                    const unsigned hi = (unsigned short)f2bf(sc[mt][2*rp+1] * rs);
                    *(unsigned*)&s_p[h*4352 + qtok*68 + ktok] = lo | (hi << 16);
                }
        }
    }
    __syncthreads();

    // ---------------- P6: out^T = V^T · P  -> s_attn (in s_xw region) ---------------
    {
        const int h = wv >> 1, mh = wv & 1;
        short8 av[2];
        #pragma unroll
        for (int ks = 0; ks < 2; ++ks)
            av[ks] = *(const short8*)&s_vT[(32*h + 16*mh + l15)*72 + ks*32 + quad*8];
        f32x4 po[4];
        #pragma unroll
        for (int nt = 0; nt < 4; ++nt) po[nt] = zf;
        #pragma unroll
        for (int nt = 0; nt < 4; ++nt)
            #pragma unroll
            for (int ks = 0; ks < 2; ++ks){
                const short8 bp = *(const short8*)&s_p[h*4352 + (16*nt + l15)*68 + ks*32 + quad*8];
                po[nt] = MFMA(av[ks], bp, po[nt]);
            }
        #pragma unroll
        for (int nt = 0; nt < 4; ++nt){
            const int qtok = 16*nt + l15;
            #pragma unroll
            for (int rp = 0; rp < 2; ++rp){
                const int drow = 32*h + 16*mh + 4*quad + 2*rp;
                const unsigned lo = (unsigned short)f2bf(po[nt][2*rp]);
                const unsigned hi = (unsigned short)f2bf(po[nt][2*rp+1]);
                *(unsigned*)&s_xw[qtok*136 + drow] = lo | (hi << 16);   // attn[tok][cin]
            }
        }
    }
    __syncthreads();

    // ---------------- P7: final^T = o_w^T · attn -> s_outT (f32, stride 66) ---------
    {
        f32x4 oc[4];
        #pragma unroll
        for (int nt = 0; nt < 4; ++nt) oc[nt] = zf;
        #pragma unroll
        for (int ks = 0; ks < 4; ++ks){
            const int co = ks*32 + quad*8;
            const short8 aw = *(const short8*)&ow[(16*wv + l15)*128 + co];
            #pragma unroll
            for (int nt = 0; nt < 4; ++nt){
                const short8 bt = *(const short8*)&s_xw[(16*nt + l15)*136 + co];
                oc[nt] = MFMA(aw, bt, oc[nt]);
            }
        }
        const float4 ob = *(const float4*)&o_b[16*wv + 4*quad];
        const float obr[4] = {ob.x, ob.y, ob.z, ob.w};
        #pragma unroll
        for (int nt = 0; nt < 4; ++nt){
            const int tok = 16*nt + l15;
            #pragma unroll
            for (int r = 0; r < 4; ++r){
                const int cout = 16*wv + 4*quad + r;
                s_outT[cout*66 + tok] = oc[nt][r] + obr[r];
            }
        }
    }
    __syncthreads();

    // ---------------- P8: coalesced store with inverse roll -------------------------
    {
        const int chan = t & 127;
        #pragma unroll
        for (int it = 0; it < 16; ++it){
            const int tok = (t >> 7) + it*4;
            const int i = tok >> 3, j = tok & 7;
            const int orow = (wy*8 + i + SHIFT_) & 255;
            const int ocol = (wx*8 + j + SHIFT_) & 255;
            out[(((size_t)bb*IMG_ + orow)*IMG_ + ocol)*C_ + chan] = s_outT[chan*66 + tok];
        }
    }
}

extern "C" void kernel_launch(void* const* d_in, const int* in_sizes, int n_in,
                              void* d_out, int out_size, void* d_ws, size_t ws_size,
                              hipStream_t stream) {
    (void)in_sizes; (void)n_in; (void)out_size; (void)ws_size;
    const float* x    = (const float*)d_in[0];
    const float* rpp  = (const float*)d_in[1];
    const float* wi_w = (const float*)d_in[2];
    const float* wi_b = (const float*)d_in[3];
    const float* w1_w = (const float*)d_in[4];
    const float* w1_b = (const float*)d_in[5];
    const float* w2_w = (const float*)d_in[6];
    const float* w2_b = (const float*)d_in[7];
    const float* q_w  = (const float*)d_in[8];
    const float* q_b  = (const float*)d_in[9];
    const float* kv_w = (const float*)d_in[10];
    const float* kv_b = (const float*)d_in[11];
    const float* o_w  = (const float*)d_in[12];
    const float* o_b  = (const float*)d_in[13];
    float* out = (float*)d_out;
    short* ws  = (short*)d_ws;

    dgwa_prep<<<dim3(256), dim3(256), 0, stream>>>(q_w, kv_w, o_w, ws);
    dgwa_fused<<<dim3(8192), dim3(512), 0, stream>>>(
        x, rpp, wi_w, wi_b, w1_w, w1_b, w2_w, w2_b,
        q_b, kv_b, o_b, ws, out);
}